// Round 6
// baseline (1002.134 us; speedup 1.0000x reference)
//
#include <hip/hip_runtime.h>
#include <stdint.h>

#define NTOK 8192   // B*T
#define DDIM 1024
#define HDIM 2048
#define ODIM 1024
#define NEXP 8

typedef unsigned short u16;
typedef short bf16x8 __attribute__((ext_vector_type(8)));
typedef float f32x4 __attribute__((ext_vector_type(4)));
typedef u16 u16x2 __attribute__((ext_vector_type(2)));

// RNE float -> bf16 (finite values)
__device__ __forceinline__ u16 f2bf(float f) {
  uint32_t u = __builtin_bit_cast(uint32_t, f);
  uint32_t r = (u + 0x7FFFu + ((u >> 16) & 1u)) >> 16;
  return (u16)r;
}

// async global->LDS: wave-uniform LDS base, HW adds lane*16B; global src per-lane.
__device__ __forceinline__ void gload16(const void* g, void* l) {
  __builtin_amdgcn_global_load_lds((__attribute__((address_space(1))) void*)(g),
                                   (__attribute__((address_space(3))) void*)(l),
                                   16, 0, 0);
}

// ---------------- init: zero output + expert counters ----------------
__global__ void init_kernel(float4* out4, int n4, int* counts) {
  int i = blockIdx.x * blockDim.x + threadIdx.x;
  if (i < NEXP) counts[i] = 0;
  for (; i < n4; i += gridDim.x * blockDim.x)
    out4[i] = make_float4(0.f, 0.f, 0.f, 0.f);
}

// -------- transpose + convert: in [E][R][C] fp32 -> out [E][C][R] bf16 --------
__global__ __launch_bounds__(256) void transpose_cvt_kernel(const float* __restrict__ in,
                                                            u16* __restrict__ out,
                                                            int R, int C) {
  __shared__ u16 lds[64 * 66];
  int e = blockIdx.z;
  int c0 = blockIdx.x * 64, r0 = blockIdx.y * 64;
  const float* ip = in + (size_t)e * R * C;
  u16* op = out + (size_t)e * R * C;
  int t = threadIdx.x;
#pragma unroll
  for (int i = 0; i < 16; i++) {
    int idx = t + 256 * i;
    int r = idx >> 6, c = idx & 63;
    lds[r * 66 + c] = f2bf(ip[(size_t)(r0 + r) * C + (c0 + c)]);
  }
  __syncthreads();
#pragma unroll
  for (int j = 0; j < 8; j++) {
    int p = t + 256 * j;
    int c = p >> 5, rp = p & 31;
    u16x2 v;
    v.x = lds[(rp * 2) * 66 + c];
    v.y = lds[(rp * 2 + 1) * 66 + c];
    *reinterpret_cast<u16x2*>(&op[(size_t)(c0 + c) * R + (r0 + rp * 2)]) = v;
  }
}

// ------- gating: fp32 logits, top-2, block-aggregated routing, fused x->bf16 -------
// 1024 threads = 16 waves = 16 tokens per block. 8 parallel global atomics per block.
__global__ __launch_bounds__(1024) void gate_kernel(const float* __restrict__ x,
                                                    const float* __restrict__ gW,
                                                    const float* __restrict__ gb,
                                                    u16* __restrict__ xbf,
                                                    int* __restrict__ counts,
                                                    int* __restrict__ lists,
                                                    float* __restrict__ wslot) {
  __shared__ int se[16][2];
  __shared__ int lpos[16][2];
  __shared__ int cntloc[NEXP], base[NEXP];
  int wv = threadIdx.x >> 6, lane = threadIdx.x & 63;
  int t = blockIdx.x * 16 + wv;
  const float* xr = x + (size_t)t * DDIM;
  u16* xbr = xbf + (size_t)t * DDIM;
  float acc[NEXP] = {};
#pragma unroll 4
  for (int i = 0; i < DDIM / 64; i++) {
    int d = lane + 64 * i;
    float xv = xr[d];
    xbr[d] = f2bf(xv);
    const float4* gr = reinterpret_cast<const float4*>(gW + (size_t)d * NEXP);
    float4 g0 = gr[0], g1 = gr[1];
    acc[0] = fmaf(xv, g0.x, acc[0]);
    acc[1] = fmaf(xv, g0.y, acc[1]);
    acc[2] = fmaf(xv, g0.z, acc[2]);
    acc[3] = fmaf(xv, g0.w, acc[3]);
    acc[4] = fmaf(xv, g1.x, acc[4]);
    acc[5] = fmaf(xv, g1.y, acc[5]);
    acc[6] = fmaf(xv, g1.z, acc[6]);
    acc[7] = fmaf(xv, g1.w, acc[7]);
  }
#pragma unroll
  for (int off = 32; off > 0; off >>= 1) {
#pragma unroll
    for (int e2 = 0; e2 < NEXP; e2++) acc[e2] += __shfl_xor(acc[e2], off, 64);
  }
  if (lane == 0) {
    float l[NEXP];
#pragma unroll
    for (int e2 = 0; e2 < NEXP; e2++) l[e2] = acc[e2] + gb[e2];
    int e0 = 0; float b0 = l[0];
#pragma unroll
    for (int e2 = 1; e2 < NEXP; e2++) if (l[e2] > b0) { b0 = l[e2]; e0 = e2; }
    int e1 = -1; float b1v = -3e38f;
#pragma unroll
    for (int e2 = 0; e2 < NEXP; e2++) if (e2 != e0 && l[e2] > b1v) { b1v = l[e2]; e1 = e2; }
    // softmax over all experts then L1-renorm of top-2 == 2-way softmax of top-2 logits
    float r = expf(b1v - b0);
    wslot[t * 2]     = 1.f / (1.f + r);
    wslot[t * 2 + 1] = r / (1.f + r);
    se[wv][0] = e0;
    se[wv][1] = e1;
  }
  __syncthreads();
  if (threadIdx.x == 0) {
    int c[NEXP] = {};
    for (int w = 0; w < 16; w++)
      for (int j = 0; j < 2; j++) { int ee = se[w][j]; lpos[w][j] = c[ee]++; }
    for (int ee = 0; ee < NEXP; ee++) cntloc[ee] = c[ee];
  }
  __syncthreads();
  if (threadIdx.x < NEXP) base[threadIdx.x] = atomicAdd(&counts[threadIdx.x], cntloc[threadIdx.x]);
  __syncthreads();
  if (threadIdx.x < 32) {
    int w = threadIdx.x >> 1, j = threadIdx.x & 1;
    int ee = se[w][j];
    lists[ee * NTOK + base[ee] + lpos[w][j]] = (blockIdx.x * 16 + w) * 2 + j;
  }
}

// ------------- grouped GEMM: 256x256 tile, BK=64, 8 waves, 2-phase dbuf -------------
// MODE 1: h = relu(x_bf16[token] @ W1T[e]^T + b1[e]) -> hbuf[slot] (bf16)
// MODE 2: out[token] += w[slot] * (hbuf[slot] @ W2T[e]^T + b2[e])   (fp32 atomic)
#define BM 256
#define BN 256
#define BK 64

template <int MODE, int K, int N>
__global__ __launch_bounds__(512, 2) void moe_gemm(const u16* __restrict__ Abase,
                                                   const u16* __restrict__ Bbase,
                                                   const int* __restrict__ counts,
                                                   const int* __restrict__ lists,
                                                   const float* __restrict__ bias,
                                                   const float* __restrict__ wslot,
                                                   u16* __restrict__ Hout,
                                                   float* __restrict__ Out) {
  int e = blockIdx.z;
  int cnt = counts[e];
  int m0 = blockIdx.x * BM;
  if (m0 >= cnt) return;
  int n0 = blockIdx.y * BN;

  __shared__ u16 As[2 * BM * BK];   // 64 KB, [buf][row][k] linear
  __shared__ u16 Bs[2 * BN * BK];   // 64 KB
  __shared__ int rowids[BM];
  __shared__ int slotids[BM];

  int tid = threadIdx.x;
  if (tid < BM) {
    int pos = m0 + tid;
    int cl = pos < cnt ? pos : cnt - 1;
    int slot = lists[e * NTOK + cl];
    slotids[tid] = slot;
    rowids[tid] = (MODE == 1) ? (slot >> 1) : slot;
  }
  __syncthreads();

  int wid = tid >> 6, lane = tid & 63;
  int wr = wid >> 2, wc = wid & 3;  // 2x4 waves; wave tile 128x64

  // staging: issue i covers rows [i*64, i*64+64); thread -> row i*64 + (tid>>3), k-chunk (tid&7)*8
  int srow = tid >> 3;
  int scol = (tid & 7) * 8;
  const u16* Bexp = Bbase + (size_t)e * N * K;
  const u16* gA[4];
  const u16* gB[4];
#pragma unroll
  for (int i = 0; i < 4; i++) {
    gA[i] = Abase + (size_t)rowids[i * 64 + srow] * K + scol;
    gB[i] = Bexp + (size_t)(n0 + i * 64 + srow) * K + scol;
  }

  // wave-uniform LDS staging bases: wave w writes rows [i*64 + w*8, +8)
  u16* aw = As + wid * 512;
  u16* bw = Bs + wid * 512;

  f32x4 acc[8][4] = {};

  // prologue: stage K-tile 0 into buf 0
#pragma unroll
  for (int i = 0; i < 4; i++) {
    gload16(gA[i], aw + i * 4096);
    gload16(gB[i], bw + i * 4096);
  }
  __syncthreads();  // drains vmcnt(0): buf0 ready

  const int NT = K / BK;
  int mr = lane & 15;
  int kq = (lane >> 4) * 8;
  for (int kt = 0; kt < NT; kt++) {
    int cur = kt & 1;
    if (kt + 1 < NT) {  // issue next-tile loads FIRST (overlap with ds_read+MFMA)
      int k0 = (kt + 1) * BK;
      u16* al = aw + (cur ^ 1) * (BM * BK);
      u16* bl = bw + (cur ^ 1) * (BN * BK);
#pragma unroll
      for (int i = 0; i < 4; i++) {
        gload16(gA[i] + k0, al + i * 4096);
        gload16(gB[i] + k0, bl + i * 4096);
      }
    }
    const u16* Ac = As + cur * (BM * BK);
    const u16* Bc = Bs + cur * (BN * BK);
#pragma unroll
    for (int ks = 0; ks < 2; ks++) {
      bf16x8 a[8], b[4];
#pragma unroll
      for (int im = 0; im < 8; im++)
        a[im] = *reinterpret_cast<const bf16x8*>(
            &Ac[(wr * 128 + im * 16 + mr) * BK + ks * 32 + kq]);
#pragma unroll
      for (int jn = 0; jn < 4; jn++)
        b[jn] = *reinterpret_cast<const bf16x8*>(
            &Bc[(wc * 64 + jn * 16 + mr) * BK + ks * 32 + kq]);
#pragma unroll
      for (int im = 0; im < 8; im++)
#pragma unroll
        for (int jn = 0; jn < 4; jn++)
          acc[im][jn] = __builtin_amdgcn_mfma_f32_16x16x32_bf16(a[im], b[jn], acc[im][jn], 0, 0, 0);
    }
    __syncthreads();  // one barrier per K-tile: drains prefetch + protects dbuf swap
  }

  // epilogue: C/D layout col = lane&15, row = (lane>>4)*4 + reg
  int coln = lane & 15;
  int rowg = (lane >> 4) * 4;
  float bj[4];
#pragma unroll
  for (int jn = 0; jn < 4; jn++)
    bj[jn] = bias[(size_t)e * N + n0 + wc * 64 + jn * 16 + coln];
#pragma unroll
  for (int im = 0; im < 8; im++) {
#pragma unroll
    for (int rr = 0; rr < 4; rr++) {
      int mloc = wr * 128 + im * 16 + rowg + rr;
      int pos = m0 + mloc;
      if (pos >= cnt) continue;
      int slot = slotids[mloc];
      if (MODE == 1) {
        size_t hrow = (size_t)slot * HDIM;
#pragma unroll
        for (int jn = 0; jn < 4; jn++) {
          int n = n0 + wc * 64 + jn * 16 + coln;
          float v = fmaxf(acc[im][jn][rr] + bj[jn], 0.0f);
          Hout[hrow + n] = f2bf(v);
        }
      } else {
        float w = wslot[slot];
        size_t orow = (size_t)(slot >> 1) * ODIM;
#pragma unroll
        for (int jn = 0; jn < 4; jn++) {
          int n = n0 + wc * 64 + jn * 16 + coln;
          unsafeAtomicAdd(&Out[orow + n], (acc[im][jn][rr] + bj[jn]) * w);
        }
      }
    }
  }
}

extern "C" void kernel_launch(void* const* d_in, const int* in_sizes, int n_in,
                              void* d_out, int out_size, void* d_ws, size_t ws_size,
                              hipStream_t stream) {
  const float* x  = (const float*)d_in[0];
  const float* gW = (const float*)d_in[1];
  const float* gb = (const float*)d_in[2];
  const float* W1 = (const float*)d_in[3];
  const float* b1 = (const float*)d_in[4];
  const float* W2 = (const float*)d_in[5];
  const float* b2 = (const float*)d_in[6];
  float* out = (float*)d_out;

  char* ws = (char*)d_ws;
  size_t off = 0;
  auto alloc = [&](size_t bytes) {
    void* p = ws + off;
    off = (off + bytes + 255) & ~(size_t)255;
    return p;
  };
  u16* xbf    = (u16*)alloc((size_t)NTOK * DDIM * 2);            // 16 MB
  u16* W1T    = (u16*)alloc((size_t)NEXP * HDIM * DDIM * 2);     // 32 MB  [E][H][D]
  u16* W2T    = (u16*)alloc((size_t)NEXP * ODIM * HDIM * 2);     // 32 MB  [E][O][H]
  u16* hbuf   = (u16*)alloc((size_t)NTOK * 2 * HDIM * 2);        // 64 MB  [slot][H]
  float* wsl  = (float*)alloc((size_t)NTOK * 2 * 4);             // 64 KB
  int* counts = (int*)alloc(64);
  int* lists  = (int*)alloc((size_t)NEXP * NTOK * 4);            // 256 KB

  init_kernel<<<2048, 256, 0, stream>>>((float4*)out, NTOK * ODIM / 4, counts);
  transpose_cvt_kernel<<<dim3(HDIM / 64, DDIM / 64, NEXP), 256, 0, stream>>>(W1, W1T, DDIM, HDIM);
  transpose_cvt_kernel<<<dim3(ODIM / 64, HDIM / 64, NEXP), 256, 0, stream>>>(W2, W2T, HDIM, ODIM);
  gate_kernel<<<NTOK / 16, 1024, 0, stream>>>(x, gW, gb, xbf, counts, lists, wsl);
  moe_gemm<1, DDIM, HDIM><<<dim3(NTOK / BM, HDIM / BN, NEXP), 512, 0, stream>>>(
      xbf, W1T, counts, lists, b1, wsl, hbuf, nullptr);
  moe_gemm<2, HDIM, ODIM><<<dim3(NTOK / BM, ODIM / BN, NEXP), 512, 0, stream>>>(
      hbuf, W2T, counts, lists, b2, wsl, nullptr, out);
}

// Round 7
// 533.322 us; speedup vs baseline: 1.8790x; 1.8790x over previous
//
#include <hip/hip_runtime.h>
#include <stdint.h>

#define NTOK 8192   // B*T
#define DDIM 1024
#define HDIM 2048
#define ODIM 1024
#define NEXP 8

typedef unsigned short u16;
typedef short bf16x8 __attribute__((ext_vector_type(8)));
typedef float f32x4 __attribute__((ext_vector_type(4)));
typedef u16 u16x2 __attribute__((ext_vector_type(2)));

// RNE float -> bf16 (finite values)
__device__ __forceinline__ u16 f2bf(float f) {
  uint32_t u = __builtin_bit_cast(uint32_t, f);
  uint32_t r = (u + 0x7FFFu + ((u >> 16) & 1u)) >> 16;
  return (u16)r;
}

// async global->LDS: wave-uniform LDS base, HW adds lane*16B; global src per-lane.
__device__ __forceinline__ void gload16(const void* g, void* l) {
  __builtin_amdgcn_global_load_lds((__attribute__((address_space(1))) void*)(g),
                                   (__attribute__((address_space(3))) void*)(l),
                                   16, 0, 0);
}

// ---------------- init: zero output + expert counters ----------------
__global__ void init_kernel(float4* out4, int n4, int* counts) {
  int i = blockIdx.x * blockDim.x + threadIdx.x;
  if (i < NEXP) counts[i] = 0;
  for (; i < n4; i += gridDim.x * blockDim.x)
    out4[i] = make_float4(0.f, 0.f, 0.f, 0.f);
}

// -------- transpose + convert: in [E][R][C] fp32 -> out [E][C][R] bf16 --------
__global__ __launch_bounds__(256) void transpose_cvt_kernel(const float* __restrict__ in,
                                                            u16* __restrict__ out,
                                                            int R, int C) {
  __shared__ u16 lds[64 * 66];
  int e = blockIdx.z;
  int c0 = blockIdx.x * 64, r0 = blockIdx.y * 64;
  const float* ip = in + (size_t)e * R * C;
  u16* op = out + (size_t)e * R * C;
  int t = threadIdx.x;
#pragma unroll
  for (int i = 0; i < 16; i++) {
    int idx = t + 256 * i;
    int r = idx >> 6, c = idx & 63;
    lds[r * 66 + c] = f2bf(ip[(size_t)(r0 + r) * C + (c0 + c)]);
  }
  __syncthreads();
#pragma unroll
  for (int j = 0; j < 8; j++) {
    int p = t + 256 * j;
    int c = p >> 5, rp = p & 31;
    u16x2 v;
    v.x = lds[(rp * 2) * 66 + c];
    v.y = lds[(rp * 2 + 1) * 66 + c];
    *reinterpret_cast<u16x2*>(&op[(size_t)(c0 + c) * R + (r0 + rp * 2)]) = v;
  }
}

// ------- gating: fp32 logits, top-2, block-aggregated routing, fused x->bf16 -------
// 1024 threads = 16 waves = 16 tokens per block. 8 parallel global atomics per block.
__global__ __launch_bounds__(1024) void gate_kernel(const float* __restrict__ x,
                                                    const float* __restrict__ gW,
                                                    const float* __restrict__ gb,
                                                    u16* __restrict__ xbf,
                                                    int* __restrict__ counts,
                                                    int* __restrict__ lists,
                                                    float* __restrict__ wslot) {
  __shared__ int se[16][2];
  __shared__ int lpos[16][2];
  __shared__ int cntloc[NEXP], base[NEXP];
  int wv = threadIdx.x >> 6, lane = threadIdx.x & 63;
  int t = blockIdx.x * 16 + wv;
  const float* xr = x + (size_t)t * DDIM;
  u16* xbr = xbf + (size_t)t * DDIM;
  float acc[NEXP] = {};
#pragma unroll 4
  for (int i = 0; i < DDIM / 64; i++) {
    int d = lane + 64 * i;
    float xv = xr[d];
    xbr[d] = f2bf(xv);
    const float4* gr = reinterpret_cast<const float4*>(gW + (size_t)d * NEXP);
    float4 g0 = gr[0], g1 = gr[1];
    acc[0] = fmaf(xv, g0.x, acc[0]);
    acc[1] = fmaf(xv, g0.y, acc[1]);
    acc[2] = fmaf(xv, g0.z, acc[2]);
    acc[3] = fmaf(xv, g0.w, acc[3]);
    acc[4] = fmaf(xv, g1.x, acc[4]);
    acc[5] = fmaf(xv, g1.y, acc[5]);
    acc[6] = fmaf(xv, g1.z, acc[6]);
    acc[7] = fmaf(xv, g1.w, acc[7]);
  }
#pragma unroll
  for (int off = 32; off > 0; off >>= 1) {
#pragma unroll
    for (int e2 = 0; e2 < NEXP; e2++) acc[e2] += __shfl_xor(acc[e2], off, 64);
  }
  if (lane == 0) {
    float l[NEXP];
#pragma unroll
    for (int e2 = 0; e2 < NEXP; e2++) l[e2] = acc[e2] + gb[e2];
    int e0 = 0; float b0 = l[0];
#pragma unroll
    for (int e2 = 1; e2 < NEXP; e2++) if (l[e2] > b0) { b0 = l[e2]; e0 = e2; }
    int e1 = -1; float b1v = -3e38f;
#pragma unroll
    for (int e2 = 0; e2 < NEXP; e2++) if (e2 != e0 && l[e2] > b1v) { b1v = l[e2]; e1 = e2; }
    // softmax over all experts then L1-renorm of top-2 == 2-way softmax of top-2 logits
    float r = expf(b1v - b0);
    wslot[t * 2]     = 1.f / (1.f + r);
    wslot[t * 2 + 1] = r / (1.f + r);
    se[wv][0] = e0;
    se[wv][1] = e1;
  }
  __syncthreads();
  if (threadIdx.x == 0) {
    int c[NEXP] = {};
    for (int w = 0; w < 16; w++)
      for (int j = 0; j < 2; j++) { int ee = se[w][j]; lpos[w][j] = c[ee]++; }
    for (int ee = 0; ee < NEXP; ee++) cntloc[ee] = c[ee];
  }
  __syncthreads();
  if (threadIdx.x < NEXP) base[threadIdx.x] = atomicAdd(&counts[threadIdx.x], cntloc[threadIdx.x]);
  __syncthreads();
  if (threadIdx.x < 32) {
    int w = threadIdx.x >> 1, j = threadIdx.x & 1;
    int ee = se[w][j];
    lists[ee * NTOK + base[ee] + lpos[w][j]] = (blockIdx.x * 16 + w) * 2 + j;
  }
}

#define BM 128
#define BN 128
#define BK 32
#define MAXPAN (16384 / BM + NEXP)   // sum of per-expert panel counts <= 136

// ---- panel schedule: dense list of (expert, m0) so every GEMM block is active ----
__global__ void sched_kernel(const int* __restrict__ counts, int* __restrict__ pan) {
  if (threadIdx.x == 0) {
    int p = 0;
    for (int e = 0; e < NEXP; e++) {
      int c = counts[e];
      for (int m0 = 0; m0 < c; m0 += BM) {
        pan[1 + 2 * p] = e;
        pan[2 + 2 * p] = m0;
        p++;
      }
    }
    pan[0] = p;
  }
}

// ---------------- grouped GEMM (m97 structure, gathered A rows, compact grid) ------
// MODE 1: h = relu(x_bf16[token] @ W1T[e]^T + b1[e]) -> hbuf[slot] (bf16)
// MODE 2: out[token] += w[slot] * (hbuf[slot] @ W2T[e]^T + b2[e])   (fp32 atomic)
template <int MODE, int K, int N>
__global__ __launch_bounds__(256, 2) void moe_gemm(const u16* __restrict__ Abase,
                                                   const u16* __restrict__ Bbase,
                                                   const int* __restrict__ counts,
                                                   const int* __restrict__ lists,
                                                   const int* __restrict__ pan,
                                                   const float* __restrict__ bias,
                                                   const float* __restrict__ wslot,
                                                   u16* __restrict__ Hout,
                                                   float* __restrict__ Out) {
  int p = blockIdx.x;
  if (p >= pan[0]) return;
  int e = pan[1 + 2 * p];
  int m0 = pan[2 + 2 * p];
  int cnt = counts[e];
  int n0 = blockIdx.y * BN;

  __shared__ u16 As[BM * BK];
  __shared__ u16 Bs[BN * BK];
  __shared__ int rowids[BM];
  __shared__ int slotids[BM];

  int tid = threadIdx.x;
  if (tid < BM) {
    int pos = m0 + tid;
    int cl = pos < cnt ? pos : cnt - 1;
    int slot = lists[e * NTOK + cl];
    slotids[tid] = slot;
    rowids[tid] = (MODE == 1) ? (slot >> 1) : slot;
  }
  __syncthreads();

  int wid = tid >> 6, lane = tid & 63;
  int wr = wid >> 1, wc = wid & 1;  // 2x2 waves, each owns 64x64 of the 128x128 tile

  int srow = tid >> 2;          // staging row (chunk 0); chunk 1 = +64
  int scol = (tid & 3) * 8;     // staging k-offset (8 bf16 = 16B)

  const u16* Bexp = Bbase + (size_t)e * N * K;
  const u16* gA0 = Abase + (size_t)rowids[srow] * K + scol;
  const u16* gA1 = Abase + (size_t)rowids[srow + 64] * K + scol;
  const u16* gB0 = Bexp + (size_t)(n0 + srow) * K + scol;
  const u16* gB1 = Bexp + (size_t)(n0 + srow + 64) * K + scol;

  u16* lA0 = As + wid * 512;
  u16* lA1 = As + 2048 + wid * 512;
  u16* lB0 = Bs + wid * 512;
  u16* lB1 = Bs + 2048 + wid * 512;

  f32x4 acc[4][4] = {};

  for (int k0 = 0; k0 < K; k0 += BK) {
    __syncthreads();
    gload16(gA0 + k0, lA0);
    gload16(gA1 + k0, lA1);
    gload16(gB0 + k0, lB0);
    gload16(gB1 + k0, lB1);
    __syncthreads();

    bf16x8 a[4], b[4];
    int mr = lane & 15;
    int kc = (lane >> 4) * 8;
#pragma unroll
    for (int i = 0; i < 4; i++)
      a[i] = *reinterpret_cast<const bf16x8*>(&As[(wr * 64 + i * 16 + mr) * BK + kc]);
#pragma unroll
    for (int j = 0; j < 4; j++)
      b[j] = *reinterpret_cast<const bf16x8*>(&Bs[(wc * 64 + j * 16 + mr) * BK + kc]);
#pragma unroll
    for (int i = 0; i < 4; i++)
#pragma unroll
      for (int j = 0; j < 4; j++)
        acc[i][j] = __builtin_amdgcn_mfma_f32_16x16x32_bf16(a[i], b[j], acc[i][j], 0, 0, 0);
  }

  // epilogue: C/D layout col = lane&15, row = (lane>>4)*4 + reg
  int coln = lane & 15;
  int rowg = (lane >> 4) * 4;
#pragma unroll
  for (int i = 0; i < 4; i++) {
#pragma unroll
    for (int rr = 0; rr < 4; rr++) {
      int mloc = wr * 64 + i * 16 + rowg + rr;
      int pos = m0 + mloc;
      if (pos >= cnt) continue;
      int slot = slotids[mloc];
      if (MODE == 1) {
        size_t hrow = (size_t)slot * HDIM;
#pragma unroll
        for (int j = 0; j < 4; j++) {
          int n = n0 + wc * 64 + j * 16 + coln;
          float v = acc[i][j][rr] + bias[(size_t)e * N + n];
          v = fmaxf(v, 0.0f);
          Hout[hrow + n] = f2bf(v);
        }
      } else {
        float w = wslot[slot];
        size_t orow = (size_t)(slot >> 1) * ODIM;
#pragma unroll
        for (int j = 0; j < 4; j++) {
          int n = n0 + wc * 64 + j * 16 + coln;
          float v = (acc[i][j][rr] + bias[(size_t)e * N + n]) * w;
          unsafeAtomicAdd(&Out[orow + n], v);
        }
      }
    }
  }
}

extern "C" void kernel_launch(void* const* d_in, const int* in_sizes, int n_in,
                              void* d_out, int out_size, void* d_ws, size_t ws_size,
                              hipStream_t stream) {
  const float* x  = (const float*)d_in[0];
  const float* gW = (const float*)d_in[1];
  const float* gb = (const float*)d_in[2];
  const float* W1 = (const float*)d_in[3];
  const float* b1 = (const float*)d_in[4];
  const float* W2 = (const float*)d_in[5];
  const float* b2 = (const float*)d_in[6];
  float* out = (float*)d_out;

  char* ws = (char*)d_ws;
  size_t off = 0;
  auto alloc = [&](size_t bytes) {
    void* p = ws + off;
    off = (off + bytes + 255) & ~(size_t)255;
    return p;
  };
  u16* xbf    = (u16*)alloc((size_t)NTOK * DDIM * 2);            // 16 MB
  u16* W1T    = (u16*)alloc((size_t)NEXP * HDIM * DDIM * 2);     // 32 MB  [E][H][D]
  u16* W2T    = (u16*)alloc((size_t)NEXP * ODIM * HDIM * 2);     // 32 MB  [E][O][H]
  u16* hbuf   = (u16*)alloc((size_t)NTOK * 2 * HDIM * 2);        // 64 MB  [slot][H]
  float* wsl  = (float*)alloc((size_t)NTOK * 2 * 4);             // 64 KB
  int* counts = (int*)alloc(64);
  int* lists  = (int*)alloc((size_t)NEXP * NTOK * 4);            // 256 KB
  int* pan    = (int*)alloc((1 + 2 * MAXPAN) * 4);               // panel table

  init_kernel<<<2048, 256, 0, stream>>>((float4*)out, NTOK * ODIM / 4, counts);
  transpose_cvt_kernel<<<dim3(HDIM / 64, DDIM / 64, NEXP), 256, 0, stream>>>(W1, W1T, DDIM, HDIM);
  transpose_cvt_kernel<<<dim3(ODIM / 64, HDIM / 64, NEXP), 256, 0, stream>>>(W2, W2T, HDIM, ODIM);
  gate_kernel<<<NTOK / 16, 1024, 0, stream>>>(x, gW, gb, xbf, counts, lists, wsl);
  sched_kernel<<<1, 64, 0, stream>>>(counts, pan);
  moe_gemm<1, DDIM, HDIM><<<dim3(MAXPAN, HDIM / BN), 256, 0, stream>>>(
      xbf, W1T, counts, lists, pan, b1, wsl, hbuf, nullptr);
  moe_gemm<2, HDIM, ODIM><<<dim3(MAXPAN, ODIM / BN), 256, 0, stream>>>(
      hbuf, W2T, counts, lists, pan, b2, wsl, nullptr, out);
}